// Round 2
// 217.344 us; speedup vs baseline: 1.0034x; 1.0034x over previous
//
#include <hip/hip_runtime.h>
#include <float.h>

#define Bn 2
#define Nn 8192
#define Rr 2048
#define Kk 16
#define CIN 64
#define CL 16
#define COUT 128
#define K2c 256
#define GT (Bn*Rr)      // 4096 groups
#define FD (CL+CIN)     // 80
#define KC (Kk*FD)      // 1280
#define MG 4            // mlp groups per block
#define CCAP 192        // knn candidate cap (3*64); expected count ~55

// ---------------- prep: weight transposes / permute + pts4 packing ----------------
__global__ __launch_bounds__(256) void prep_kernel(
    const float* __restrict__ t1_w, const float* __restrict__ t2_w,
    const float* __restrict__ t3_w, const float* __restrict__ conv_w,
    const float* __restrict__ points,
    float* __restrict__ t1t, float* __restrict__ t2t,
    float* __restrict__ t3t, float* __restrict__ wp,
    float4* __restrict__ pts4)
{
  int i = blockIdx.x * 256 + threadIdx.x;
  if (i < K2c*48) { int j = i / 48, k = i - j*48; t1t[k*K2c + j] = t1_w[i]; }
  if (i < K2c*K2c) { int j = i >> 8, k = i & 255; t2t[k*K2c + j] = t2_w[i]; t3t[k*K2c + j] = t3_w[i]; }
  if (i < COUT*KC) {
    int o = i / KC, ck = i - o*KC;
    int c = ck >> 4, k = ck & 15;
    wp[(k*FD + c)*COUT + o] = conv_w[i];
  }
  if (i < Bn*Nn) {
    float x = points[i*3+0], y = points[i*3+1], z = points[i*3+2];
    // numpy order: sq = (x*x + y*y) + z*z, muls materialized then summed
    float sq = __fadd_rn(__fadd_rn(__fmul_rn(x,x), __fmul_rn(y,y)), __fmul_rn(z,z));
    pts4[i] = make_float4(x, y, z, sq);
  }
}

// ---------------- knn v7: point-parallel + v5.1-grade tau via c-transpose ----------------
// v6 post-mortem: per-thread top-3 of 16 pts gave a tau at global rank ~320
// with a fat tail -> CCAP=384 overflowed for some queries -> dropped true
// top-17 members -> absmax 6.08. v7 keeps the point-parallel nest (each LDS
// point read ONCE per block, queries in SGPRs: the 8x LDS-traffic win) but
// computes tau with v5.1-grade statistics: transpose all 512 threads'
// (c0,c1,c2) per query into LDS (48 KB, unioned with the points buffer),
// wave w re-selects top-3-of-24 per lane for query w and runs the proven
// 6-pop wave-min. Every popped lane bounds 3 REAL distances (all 1536
// c-values are finite: each thread saw 16 >= 3 points), so >=18 entries
// <= tau. Count{d2<=tau} ~ first-6-distinct-triples over 64 bins ~= 53;
// P(count > 192) ~ e^-283. Pass-2 d2 expressions bit-identical to pass 1.
// Cost of the union: chunk-3-resident trick dropped; pass 2 re-stages all
// 4 chunks (one extra 32 KB L2 stage per block, ~0.5 us total).
__global__ __launch_bounds__(512, 4) void knn_kernel(
    const float4* __restrict__ pts4, const int* __restrict__ rep_idx,
    int* __restrict__ nb_idx, float* __restrict__ p_out,
    float* __restrict__ rep_pos_out)
{
  union SmemU {
    float4 ptsS[2048];        // 32 KB chunk
    float  cbuf[8][1536];     // 48 KB c-transpose: [q][i*512 + t]
  };
  __shared__ SmemU U;
  __shared__ unsigned long long coll[8][CCAP];        // 12 KB candidates
  __shared__ float4 qS[8];
  __shared__ float  tauS[8];
  __shared__ int    ccnt[8];

  int t    = threadIdx.x;
  int lane = t & 63;
  int w    = t >> 6;                 // 0..7
  int g0   = blockIdx.x * 8;         // 8 | 2048: block never straddles batches
  int b    = g0 >> 11;
  const float4* pb4 = pts4 + (size_t)b*Nn;

  if (t < 8) {
    int g = g0 + t;
    int r = g & 2047;
    qS[t] = pb4[rep_idx[r]];
    ccnt[t] = 0;
  }
  __syncthreads();

  // queries to SGPRs (uniform across block)
  float qx[8], qy[8], qz[8], qw[8];
  #pragma unroll
  for (int q = 0; q < 8; q++) {
    float4 Q = qS[q];
    qx[q] = __uint_as_float(__builtin_amdgcn_readfirstlane(__float_as_uint(Q.x)));
    qy[q] = __uint_as_float(__builtin_amdgcn_readfirstlane(__float_as_uint(Q.y)));
    qz[q] = __uint_as_float(__builtin_amdgcn_readfirstlane(__float_as_uint(Q.z)));
    qw[q] = __uint_as_float(__builtin_amdgcn_readfirstlane(__float_as_uint(Q.w)));
  }

  // ---- pass 1: per-thread top-3 VALUES per query over 4 chunks ----
  float c0[8], c1[8], c2[8];
  #pragma unroll
  for (int q = 0; q < 8; q++) { c0[q] = FLT_MAX; c1[q] = FLT_MAX; c2[q] = FLT_MAX; }

  for (int c = 0; c < 4; c++) {
    int base = c * 2048;
    __syncthreads();
    for (int i = t; i < 2048; i += 512) U.ptsS[i] = pb4[base + i];
    __syncthreads();
    #pragma unroll
    for (int j = 0; j < 4; j++) {
      float4 P = U.ptsS[j*512 + t];
      #pragma unroll
      for (int q = 0; q < 8; q++) {
        float dot = __fmaf_rn(qz[q], P.z, __fmaf_rn(qy[q], P.y, __fmul_rn(qx[q], P.x)));
        float d2  = __fsub_rn(__fadd_rn(qw[q], P.w), __fmul_rn(2.0f, dot));
        float nc2 = __builtin_amdgcn_fmed3f(c1[q], c2[q], d2);
        float nc1 = __builtin_amdgcn_fmed3f(c0[q], c1[q], d2);
        float nc0 = fminf(c0[q], d2);
        c0[q] = nc0; c1[q] = nc1; c2[q] = nc2;
      }
    }
  }

  // ---- c-transpose: overwrite points buffer with all triples ----
  __syncthreads();   // all pass-1 ptsS reads done before union overwrite
  #pragma unroll
  for (int q = 0; q < 8; q++) {
    U.cbuf[q][0*512 + t] = c0[q];
    U.cbuf[q][1*512 + t] = c1[q];
    U.cbuf[q][2*512 + t] = c2[q];
  }
  __syncthreads();

  // ---- tau: wave w selects for query w over its 1536 c-values ----
  {
    float C0 = FLT_MAX, C1 = FLT_MAX, C2 = FLT_MAX;
    #pragma unroll
    for (int j = 0; j < 8; j++) {
      int s = lane + 64*j;
      #pragma unroll
      for (int i = 0; i < 3; i++) {
        float v = U.cbuf[w][i*512 + s];
        float n2 = __builtin_amdgcn_fmed3f(C1, C2, v);
        float n1 = __builtin_amdgcn_fmed3f(C0, C1, v);
        float n0 = fminf(C0, v);
        C0 = n0; C1 = n1; C2 = n2;
      }
    }
    float tw = FLT_MAX;
    #pragma unroll
    for (int rnd = 0; rnd < 6; rnd++) {
      float m = C2;
      #pragma unroll
      for (int off = 1; off < 64; off <<= 1) m = fminf(m, __shfl_xor(m, off));
      if (C2 == m) C2 = FLT_MAX;
      tw = m;
    }
    if (lane == 0) tauS[w] = tw;
  }
  __syncthreads();   // all cbuf reads done; tauS visible

  float tau[8];
  #pragma unroll
  for (int q = 0; q < 8; q++)
    tau[q] = __uint_as_float(__builtin_amdgcn_readfirstlane(__float_as_uint(tauS[q])));

  // ---- pass 2: re-stage all 4 chunks, predicate + collect ----
  for (int c = 0; c < 4; c++) {
    int base = c * 2048;
    __syncthreads();   // prev chunk compute done (c=0: tauS reads, safe anyway)
    for (int i = t; i < 2048; i += 512) U.ptsS[i] = pb4[base + i];
    __syncthreads();
    #pragma unroll
    for (int j = 0; j < 4; j++) {
      float4 P = U.ptsS[j*512 + t];
      int idx = base + j*512 + t;
      #pragma unroll
      for (int q = 0; q < 8; q++) {
        float dot = __fmaf_rn(qz[q], P.z, __fmaf_rn(qy[q], P.y, __fmul_rn(qx[q], P.x)));
        float d2  = __fsub_rn(__fadd_rn(qw[q], P.w), __fmul_rn(2.0f, dot));
        if (d2 <= tau[q]) {
          int pos = atomicAdd(&ccnt[q], 1);
          if (pos < CCAP) {
            unsigned f = __float_as_uint(d2);
            unsigned mono = f ^ ((unsigned)((int)f >> 31) | 0x80000000u);
            coll[q][pos] = ((unsigned long long)mono << 32) | (unsigned)idx;
          }
        }
      }
    }
  }
  __syncthreads();

  // ---- final: exact top-17 extraction (wave w owns query w), <=192 keys ----
  int cnt = ccnt[w];
  if (cnt > CCAP) cnt = CCAP;
  const unsigned long long* cw = coll[w];
  unsigned long long e[3];
  #pragma unroll
  for (int k = 0; k < 3; k++)
    e[k] = (lane + 64*k < cnt) ? cw[lane + 64*k] : ~0ull;

  int out_m = 0;
  for (int rnd = 0; rnd < 17; rnd++) {
    unsigned long long a01 = (e[0] < e[1]) ? e[0] : e[1];
    unsigned long long myk = (a01 < e[2]) ? a01 : e[2];
    unsigned long long kmin = myk;
    #pragma unroll
    for (int off = 1; off < 64; off <<= 1) {
      unsigned long long o = __shfl_xor(kmin, off);
      kmin = (o < kmin) ? o : kmin;
    }
    if (rnd >= 1 && lane == rnd - 1) out_m = (int)(kmin & 0xFFFFFFFFull);
    if      (kmin == e[0]) e[0] = ~0ull;
    else if (kmin == e[1]) e[1] = ~0ull;
    else if (kmin == e[2]) e[2] = ~0ull;
  }

  int g = g0 + w;
  float4 Q = qS[w];
  if (lane < 16) {
    nb_idx[g*Kk + lane] = out_m;
    float4 P = pb4[out_m];
    p_out[(g*Kk + lane)*3 + 0] = __fsub_rn(P.x, Q.x);
    p_out[(g*Kk + lane)*3 + 1] = __fsub_rn(P.y, Q.y);
    p_out[(g*Kk + lane)*3 + 2] = __fsub_rn(P.z, Q.z);
  }
  if (lane < 3) rep_pos_out[g*3 + lane] = (lane == 0 ? Q.x : (lane == 1 ? Q.y : Q.z));
}

// ---------------- mlp v6: MG=4, depth-4 weight prefetch (covers L2 latency) ----------------
__device__ __forceinline__ void fma_g(float4& a, float hv, const float4& wv) {
  a.x = fmaf(hv, wv.x, a.x);
  a.y = fmaf(hv, wv.y, a.y);
  a.z = fmaf(hv, wv.z, a.z);
  a.w = fmaf(hv, wv.w, a.w);
}

__global__ __launch_bounds__(256) void mlp_kernel(
    const float* __restrict__ p,
    const float* __restrict__ t1t, const float* __restrict__ t1_b,
    const float* __restrict__ g1v, const float* __restrict__ b1v,
    const float* __restrict__ t2t, const float* __restrict__ t2_b,
    const float* __restrict__ g2v, const float* __restrict__ b2v,
    const float* __restrict__ t3t, const float* __restrict__ t3_b,
    const float* __restrict__ g3v, const float* __restrict__ b3v,
    float* __restrict__ T_out)
{
  __shared__ float pf[48][MG];       // 768 B
  __shared__ float hA[K2c][MG];      // 4 KB
  __shared__ float red[4*16*66];     // 16.9 KB: red[(w*16 + comp*4 + q)*66 + lane]
  int t = threadIdx.x;
  int w = t >> 6, l = t & 63;
  int g0 = blockIdx.x * MG;
  for (int e = t; e < MG*48; e += 256) {
    int g = e / 48, k = e - g*48;
    pf[k][g] = p[(size_t)(g0+g)*48 + k];
  }
  __syncthreads();

  float4 acc[MG];   // acc[q] = group q over cols 4l..4l+3

#define LDW(WSRC, K) (*(const float4*)&WSRC[(size_t)(K)*K2c + 4*l])

#define KSTAGE(WSRC, KDIM, HBUF, WB, KK, KNEXT)                        \
  {                                                                    \
    float4 wc = WB;                                                    \
    if ((KNEXT) < KDIM) WB = LDW(WSRC, KNEXT);                         \
    float4 h = *(const float4*)&HBUF[KK][0];                           \
    fma_g(acc[0], h.x, wc); fma_g(acc[1], h.y, wc);                    \
    fma_g(acc[2], h.z, wc); fma_g(acc[3], h.w, wc);                    \
  }

#define KLOOP(WSRC, KDIM, HBUF)                                        \
  {                                                                    \
    _Pragma("unroll")                                                  \
    for (int q = 0; q < MG; q++) acc[q] = make_float4(0.f,0.f,0.f,0.f);\
    float4 wb0 = LDW(WSRC, w);                                         \
    float4 wb1 = (w + 4  < KDIM) ? LDW(WSRC, w + 4)  : wb0;            \
    float4 wb2 = (w + 8  < KDIM) ? LDW(WSRC, w + 8)  : wb0;            \
    float4 wb3 = (w + 12 < KDIM) ? LDW(WSRC, w + 12) : wb0;            \
    for (int k = w; k < KDIM; k += 16) {                               \
      KSTAGE(WSRC, KDIM, HBUF, wb0, k,      k + 16)                    \
      if (k + 4 < KDIM)  KSTAGE(WSRC, KDIM, HBUF, wb1, k + 4,  k + 20) \
      if (k + 8 < KDIM)  KSTAGE(WSRC, KDIM, HBUF, wb2, k + 8,  k + 24) \
      if (k + 12 < KDIM) KSTAGE(WSRC, KDIM, HBUF, wb3, k + 12, k + 28) \
    }                                                                  \
  }

#define WRITE_RED()                                                    \
  {                                                                    \
    _Pragma("unroll")                                                  \
    for (int q = 0; q < MG; q++) {                                     \
      red[(w*16 + 0*4 + q)*66 + l] = acc[q].x;                         \
      red[(w*16 + 1*4 + q)*66 + l] = acc[q].y;                         \
      red[(w*16 + 2*4 + q)*66 + l] = acc[q].z;                         \
      red[(w*16 + 3*4 + q)*66 + l] = acc[q].w;                         \
    }                                                                  \
  }

#define REDUCE(S)                                                      \
  float4 S = make_float4(0.f,0.f,0.f,0.f);                             \
  {                                                                    \
    int lr = t >> 2, cc = t & 3;                                       \
    _Pragma("unroll")                                                  \
    for (int ww = 0; ww < 4; ww++) {                                   \
      S.x += red[(ww*16 + cc*4 + 0)*66 + lr];                          \
      S.y += red[(ww*16 + cc*4 + 1)*66 + lr];                          \
      S.z += red[(ww*16 + cc*4 + 2)*66 + lr];                          \
      S.w += red[(ww*16 + cc*4 + 3)*66 + lr];                          \
    }                                                                  \
  }

  // ===== layer 1 (K=48), relu =====
  KLOOP(t1t, 48, pf)
  WRITE_RED()
  __syncthreads();
  {
    REDUCE(s)
    float bb = t1_b[t], gg = g1v[t], oo = b1v[t];
    float4 v;
    v.x = fmaxf(fmaf(s.x + bb, gg, oo), 0.f);
    v.y = fmaxf(fmaf(s.y + bb, gg, oo), 0.f);
    v.z = fmaxf(fmaf(s.z + bb, gg, oo), 0.f);
    v.w = fmaxf(fmaf(s.w + bb, gg, oo), 0.f);
    *(float4*)&hA[t][0] = v;
  }
  __syncthreads();

  // ===== layer 2 (K=256), relu =====
  KLOOP(t2t, K2c, hA)
  WRITE_RED()
  __syncthreads();
  {
    REDUCE(s)
    float bb = t2_b[t], gg = g2v[t], oo = b2v[t];
    float4 v;
    v.x = fmaxf(fmaf(s.x + bb, gg, oo), 0.f);
    v.y = fmaxf(fmaf(s.y + bb, gg, oo), 0.f);
    v.z = fmaxf(fmaf(s.z + bb, gg, oo), 0.f);
    v.w = fmaxf(fmaf(s.w + bb, gg, oo), 0.f);
    *(float4*)&hA[t][0] = v;
  }
  __syncthreads();

  // ===== layer 3 (K=256), no relu, to global =====
  KLOOP(t3t, K2c, hA)
  WRITE_RED()
  __syncthreads();
  {
    REDUCE(s)
    float bb = t3_b[t], gg = g3v[t], oo = b3v[t];
    T_out[(size_t)(g0+0)*K2c + t] = fmaf(s.x + bb, gg, oo);
    T_out[(size_t)(g0+1)*K2c + t] = fmaf(s.y + bb, gg, oo);
    T_out[(size_t)(g0+2)*K2c + t] = fmaf(s.z + bb, gg, oo);
    T_out[(size_t)(g0+3)*K2c + t] = fmaf(s.w + bb, gg, oo);
  }
#undef KLOOP
#undef KSTAGE
#undef LDW
#undef WRITE_RED
#undef REDUCE
}

// ---------------- tf (fused feat), 4 groups/block ----------------
__global__ __launch_bounds__(256) void tf_kernel(
    const float* __restrict__ T_in, const float* __restrict__ features,
    const float* __restrict__ p, const int* __restrict__ nb_idx,
    const float* __restrict__ lift_w, const float* __restrict__ lift_b,
    const float* __restrict__ bng, const float* __restrict__ bnb,
    float* __restrict__ Tf)
{
  __shared__ float T_s[4*K2c];    // 4 KB
  __shared__ float f_s[4*KC];     // 20 KB
  __shared__ float ps[4*48];      // 768 B
  __shared__ int   idxs[64];      // 256 B
  __shared__ float lw[48], lb2[16], lg[16], lo[16];
  int t = threadIdx.x;
  int g0 = blockIdx.x * 4;
  int b = g0 / Rr;                // 4 | 2048: block never straddles batches
  for (int e = t; e < 4*K2c; e += 256) T_s[e] = T_in[(size_t)g0*K2c + e];
  if (t >= 32 && t < 224) {
    int e = t - 32;               // 192 threads cover ps
    ps[e] = p[(size_t)g0*48 + e];
  }
  if (t < 64) idxs[t] = nb_idx[g0*16 + t];
  if (t >= 64 && t < 112)  lw[t-64]   = lift_w[t-64];
  if (t >= 112 && t < 128) lb2[t-112] = lift_b[t-112];
  if (t >= 224 && t < 240) lg[t-224]  = bng[t-224];
  if (t >= 240)            lo[t-240]  = bnb[t-240];
  __syncthreads();

  // gather neighbor features: 64 rows of 64
  {
    int wv = t >> 6, ln = t & 63;
    for (int row = wv; row < 64; row += 4) {
      int gg = row >> 4, k = row & 15;
      f_s[gg*KC + k*FD + CL + ln] = features[((size_t)b*Nn + idxs[row])*CIN + ln];
    }
  }
  // lifted BN+ReLU: 4*16*16 = 1024 elements
  for (int e = t; e < 1024; e += 256) {
    int gg = e >> 8, rem = e & 255, k = rem >> 4, c = rem & 15;
    float acc = ps[gg*48 + k*3 + 0]*lw[c*3+0] + ps[gg*48 + k*3 + 1]*lw[c*3+1]
              + ps[gg*48 + k*3 + 2]*lw[c*3+2] + lb2[c];
    acc = acc*lg[c] + lo[c];
    f_s[gg*KC + k*FD + c] = fmaxf(acc, 0.f);
  }
  __syncthreads();

  int gg = t >> 6;    // wave per group
  int cl = t & 63;
  for (int ci = cl; ci < FD; ci += 64) {
    float fcol[16];
    #pragma unroll
    for (int j = 0; j < 16; j++) fcol[j] = f_s[gg*KC + j*FD + ci];
    #pragma unroll
    for (int k = 0; k < 16; k++) {
      float acc = 0.f;
      #pragma unroll
      for (int j = 0; j < 16; j++) acc = fmaf(T_s[gg*K2c + k*16 + j], fcol[j], acc);
      Tf[(size_t)(g0+gg)*KC + k*FD + ci] = acc;
    }
  }
}

// ---------------- gemm: out = Tf(4096x1280) @ Wp(1280x128), split-K=8 ----------------
__global__ __launch_bounds__(256) void gemm_kernel(
    const float* __restrict__ A,    // Tf
    const float* __restrict__ Bm,   // Wp
    float* __restrict__ part)       // [8][GT][COUT]
{
  __shared__ float As[16*36];
  __shared__ float Bs[16*COUT];
  int t = threadIdx.x;
  int m0 = blockIdx.x * 32;
  int ky = blockIdx.y;
  int kbase0 = ky * (KC/8);         // 160
  float acc[4][4];
  #pragma unroll
  for (int i = 0; i < 4; i++)
    #pragma unroll
    for (int j = 0; j < 4; j++) acc[i][j] = 0.f;
  int tn = t & 31, tm = t >> 5;

  for (int kt = 0; kt < KC/8; kt += 16) {
    int kb = kbase0 + kt;
    {
      int kcol = t & 15, row = t >> 4;
      As[kcol*36 + row]      = A[(size_t)(m0+row)*KC + kb + kcol];
      As[kcol*36 + row + 16] = A[(size_t)(m0+row+16)*KC + kb + kcol];
    }
    {
      int o = t & 127, kk2 = t >> 7;
      #pragma unroll
      for (int p4 = 0; p4 < 8; p4++) {
        int kk = kk2 + p4*2;
        Bs[kk*COUT + o] = Bm[(size_t)(kb+kk)*COUT + o];
      }
    }
    __syncthreads();
    #pragma unroll
    for (int kk = 0; kk < 16; kk++) {
      float4 a4 = *(const float4*)&As[kk*36 + tm*4];
      float4 b4 = *(const float4*)&Bs[kk*COUT + tn*4];
      float av[4] = {a4.x, a4.y, a4.z, a4.w};
      float bv[4] = {b4.x, b4.y, b4.z, b4.w};
      #pragma unroll
      for (int i = 0; i < 4; i++)
        #pragma unroll
        for (int j = 0; j < 4; j++) acc[i][j] = fmaf(av[i], bv[j], acc[i][j]);
    }
    __syncthreads();
  }
  #pragma unroll
  for (int i = 0; i < 4; i++) {
    float4 v = make_float4(acc[i][0], acc[i][1], acc[i][2], acc[i][3]);
    *(float4*)&part[((size_t)ky*GT + m0 + tm*4 + i)*COUT + tn*4] = v;
  }
}

// ---------------- reduce: out = sum(part[0..7]) + bias ----------------
__global__ __launch_bounds__(256) void reduce_kernel(
    const float* __restrict__ part, const float* __restrict__ conv_b,
    float* __restrict__ outp)
{
  int i = blockIdx.x*256 + threadIdx.x;
  float4 s = ((const float4*)conv_b)[i & 31];
  #pragma unroll
  for (int w = 0; w < 8; w++) {
    float4 v = ((const float4*)(part + (size_t)w*GT*COUT))[i];
    s.x += v.x; s.y += v.y; s.z += v.z; s.w += v.w;
  }
  ((float4*)outp)[i] = s;
}

extern "C" void kernel_launch(void* const* d_in, const int* in_sizes, int n_in,
                              void* d_out, int out_size, void* d_ws, size_t ws_size,
                              hipStream_t stream) {
  const float* points   = (const float*)d_in[0];
  const float* features = (const float*)d_in[1];
  const float* lift_w   = (const float*)d_in[2];
  const float* lift_b   = (const float*)d_in[3];
  const float* bn_lift_g= (const float*)d_in[4];
  const float* bn_lift_b= (const float*)d_in[5];
  const float* t1_w     = (const float*)d_in[6];
  const float* t1_b     = (const float*)d_in[7];
  const float* bn1_g    = (const float*)d_in[8];
  const float* bn1_b    = (const float*)d_in[9];
  const float* t2_w     = (const float*)d_in[10];
  const float* t2_b     = (const float*)d_in[11];
  const float* bn2_g    = (const float*)d_in[12];
  const float* bn2_b    = (const float*)d_in[13];
  const float* t3_w     = (const float*)d_in[14];
  const float* t3_b     = (const float*)d_in[15];
  const float* bn3_g    = (const float*)d_in[16];
  const float* bn3_b    = (const float*)d_in[17];
  const float* conv_w   = (const float*)d_in[18];
  const float* conv_b   = (const float*)d_in[19];
  const int*   rep_idx  = (const int*)d_in[20];

  char* ws = (char*)d_ws;
  int*    nb   = (int*)   (ws + 0);          // 256 KB
  float*  p    = (float*) (ws + 262144);     // 768 KB
  float*  T    = (float*) (ws + 1048576);    // 4 MB
  float*  Tf   = (float*) (ws + 5242880);    // 20 MB
  float*  wp   = (float*) (ws + 26214400);   // 640 KB
  float*  t1t  = (float*) (ws + 26869760);   // 48 KB
  float*  t2t  = (float*) (ws + 26918912);   // 256 KB
  float*  t3t  = (float*) (ws + 27181056);   // 256 KB
  float*  part = (float*) (ws + 33554432);   // 16 MB (8 splits)
  float4* pts4 = (float4*)(ws + 52428800);   // 256 KB

  float* rep_pos = (float*)d_out;
  float* outp    = (float*)d_out + (size_t)GT*3;

  prep_kernel<<<640, 256, 0, stream>>>(t1_w, t2_w, t3_w, conv_w, points,
                                       t1t, t2t, t3t, wp, pts4);
  knn_kernel<<<GT/8, 512, 0, stream>>>(pts4, rep_idx, nb, p, rep_pos);
  mlp_kernel<<<GT/MG, 256, 0, stream>>>(p, t1t, t1_b, bn1_g, bn1_b,
                                        t2t, t2_b, bn2_g, bn2_b,
                                        t3t, t3_b, bn3_g, bn3_b, T);
  tf_kernel<<<GT/4, 256, 0, stream>>>(T, features, p, nb,
                                      lift_w, lift_b, bn_lift_g, bn_lift_b, Tf);
  dim3 ggrid(GT/32, 8);
  gemm_kernel<<<ggrid, 256, 0, stream>>>(Tf, wp, part);
  reduce_kernel<<<(GT*COUT/4)/256, 256, 0, stream>>>(part, conv_b, outp);
}

// Round 3
// 214.836 us; speedup vs baseline: 1.0152x; 1.0117x over previous
//
#include <hip/hip_runtime.h>
#include <float.h>

#define Bn 2
#define Nn 8192
#define Rr 2048
#define Kk 16
#define CIN 64
#define CL 16
#define COUT 128
#define K2c 256
#define GT (Bn*Rr)      // 4096 groups
#define FD (CL+CIN)     // 80
#define KC (Kk*FD)      // 1280
#define MG 4            // mlp groups per block
#define CCAP 128        // knn candidate cap; expected count ~53 (v5.1 statistic)

// ---------------- prep: weight transposes / permute + pts4 packing ----------------
__global__ __launch_bounds__(256) void prep_kernel(
    const float* __restrict__ t1_w, const float* __restrict__ t2_w,
    const float* __restrict__ t3_w, const float* __restrict__ conv_w,
    const float* __restrict__ points,
    float* __restrict__ t1t, float* __restrict__ t2t,
    float* __restrict__ t3t, float* __restrict__ wp,
    float4* __restrict__ pts4)
{
  int i = blockIdx.x * 256 + threadIdx.x;
  if (i < K2c*48) { int j = i / 48, k = i - j*48; t1t[k*K2c + j] = t1_w[i]; }
  if (i < K2c*K2c) { int j = i >> 8, k = i & 255; t2t[k*K2c + j] = t2_w[i]; t3t[k*K2c + j] = t3_w[i]; }
  if (i < COUT*KC) {
    int o = i / KC, ck = i - o*KC;
    int c = ck >> 4, k = ck & 15;
    wp[(k*FD + c)*COUT + o] = conv_w[i];
  }
  if (i < Bn*Nn) {
    float x = points[i*3+0], y = points[i*3+1], z = points[i*3+2];
    // numpy order: sq = (x*x + y*y) + z*z, muls materialized then summed
    float sq = __fadd_rn(__fadd_rn(__fmul_rn(x,x), __fmul_rn(y,y)), __fmul_rn(z,z));
    pts4[i] = make_float4(x, y, z, sq);
  }
}

// ---------------- knn v8: reg-resident points, rank-select tau, rank extraction ----------------
// v7 post-mortem: VALUBusy 50%, conflicts 0, HBM 0.7% -> the cost was NOT LDS
// throughput but (a) 16 stage/barrier phases exposing load latency and (b) two
// long SERIAL shuffle chains (6-pop tau = 36 dependent ds_swizzle; 17-round
// u64 extraction = ~204 dependent DS ops ~100cy each ~ 8us/wave). v8:
//  - each thread loads its 16 points ONCE into registers (L2-resident 256 KB
//    input); both passes compute from regs; 4 barriers total.
//  - pass 1 keeps only the per-thread MIN per query (7 ops/pair).
//  - tau: per lane L = 3rd-smallest of its 8 thread-minima (med3 chain, all
//    parallel); tau = 6th-smallest L over 64 lanes via RANK-SELECTION (64
//    broadcast LDS reads, no serial chain). 6 lanes x 3 bounded points ->
//    >=18 real distances <= tau. This is v5.1's harness-proven statistic
//    (6th smallest of per-128-point 3rd-order-stats): count ~53, CCAP=128.
//  - extraction: exact rank of each candidate key via broadcast-compare loop
//    (~cnt iters, parallel); rank r in [1,16] writes slot r-1. Key=(mono(d2),
//    idx) keeps reference tie-break (lower index first). d2 expressions
//    bit-identical to v5.1/v7 in both passes.
__global__ __launch_bounds__(512, 4) void knn_kernel(
    const float4* __restrict__ pts4, const int* __restrict__ rep_idx,
    int* __restrict__ nb_idx, float* __restrict__ p_out,
    float* __restrict__ rep_pos_out)
{
  __shared__ float cbuf[8][512];                 // 16 KB per-thread minima [q][t]
  __shared__ unsigned long long coll[8][CCAP];   // 8 KB candidates
  __shared__ float Lst[8][64];                   // 2 KB per-lane tau stats
  __shared__ float4 qS[8];
  __shared__ float  tauS[8];
  __shared__ int    ccnt[8];

  int t    = threadIdx.x;
  int lane = t & 63;
  int w    = t >> 6;                 // 0..7
  int g0   = blockIdx.x * 8;         // 8 | 2048: block never straddles batches
  int b    = g0 >> 11;
  const float4* pb4 = pts4 + (size_t)b*Nn;

  if (t < 8) {
    int g = g0 + t;
    int r = g & 2047;
    qS[t] = pb4[rep_idx[r]];
    ccnt[t] = 0;
  }
  __syncthreads();

  // queries to SGPRs (uniform across block)
  float qx[8], qy[8], qz[8], qw[8];
  #pragma unroll
  for (int q = 0; q < 8; q++) {
    float4 Q = qS[q];
    qx[q] = __uint_as_float(__builtin_amdgcn_readfirstlane(__float_as_uint(Q.x)));
    qy[q] = __uint_as_float(__builtin_amdgcn_readfirstlane(__float_as_uint(Q.y)));
    qz[q] = __uint_as_float(__builtin_amdgcn_readfirstlane(__float_as_uint(Q.z)));
    qw[q] = __uint_as_float(__builtin_amdgcn_readfirstlane(__float_as_uint(Q.w)));
  }

  // ---- load my 16 points into registers (coalesced, once) ----
  float4 P[16];
  #pragma unroll
  for (int i = 0; i < 16; i++) P[i] = pb4[t + 512*i];

  // ---- pass 1: per-thread min d2 per query ----
  float m[8];
  #pragma unroll
  for (int q = 0; q < 8; q++) m[q] = FLT_MAX;
  #pragma unroll
  for (int i = 0; i < 16; i++) {
    #pragma unroll
    for (int q = 0; q < 8; q++) {
      float dot = __fmaf_rn(qz[q], P[i].z, __fmaf_rn(qy[q], P[i].y, __fmul_rn(qx[q], P[i].x)));
      float d2  = __fsub_rn(__fadd_rn(qw[q], P[i].w), __fmul_rn(2.0f, dot));
      m[q] = fminf(m[q], d2);
    }
  }

  #pragma unroll
  for (int q = 0; q < 8; q++) cbuf[q][t] = m[q];
  __syncthreads();

  // ---- tau: wave w handles query w ----
  {
    // per-lane 3rd-smallest of its 8 thread-minima (bounds 3 real distances)
    float C0 = FLT_MAX, C1 = FLT_MAX, C2 = FLT_MAX;
    #pragma unroll
    for (int j = 0; j < 8; j++) {
      float v = cbuf[w][lane + 64*j];
      float n2 = __builtin_amdgcn_fmed3f(C1, C2, v);
      float n1 = __builtin_amdgcn_fmed3f(C0, C1, v);
      float n0 = fminf(C0, v);
      C0 = n0; C1 = n1; C2 = n2;
    }
    Lst[w][lane] = C2;
  }
  __syncthreads();
  {
    // tau = 6th-smallest L (rank 5, lex (L,lane) unique) -> >=18 pts <= tau
    float L = Lst[w][lane];
    int rk = 0;
    #pragma unroll 8
    for (int i = 0; i < 64; i++) {
      float Li = Lst[w][i];
      rk += (Li < L || (Li == L && i < lane)) ? 1 : 0;
    }
    if (rk == 5) tauS[w] = L;
  }
  __syncthreads();

  float tau[8];
  #pragma unroll
  for (int q = 0; q < 8; q++)
    tau[q] = __uint_as_float(__builtin_amdgcn_readfirstlane(__float_as_uint(tauS[q])));

  // ---- pass 2: recompute d2 from reg-resident points, collect candidates ----
  #pragma unroll
  for (int i = 0; i < 16; i++) {
    #pragma unroll
    for (int q = 0; q < 8; q++) {
      float dot = __fmaf_rn(qz[q], P[i].z, __fmaf_rn(qy[q], P[i].y, __fmul_rn(qx[q], P[i].x)));
      float d2  = __fsub_rn(__fadd_rn(qw[q], P[i].w), __fmul_rn(2.0f, dot));
      if (d2 <= tau[q]) {
        int pos = atomicAdd(&ccnt[q], 1);
        if (pos < CCAP) {
          unsigned f = __float_as_uint(d2);
          unsigned mono = f ^ ((unsigned)((int)f >> 31) | 0x80000000u);
          coll[q][pos] = ((unsigned long long)mono << 32) | (unsigned)(t + 512*i);
        }
      }
    }
  }
  __syncthreads();

  // ---- extraction: exact rank via broadcast-compare (no serial chains) ----
  int cnt = __builtin_amdgcn_readfirstlane(ccnt[w]);
  if (cnt > CCAP) cnt = CCAP;
  unsigned long long k1 = (lane < cnt)      ? coll[w][lane]      : ~0ull;
  unsigned long long k2 = (lane + 64 < cnt) ? coll[w][lane + 64] : ~0ull;
  int r1 = 0, r2 = 0;
  for (int i = 0; i < cnt; i++) {
    unsigned long long ki = coll[w][i];   // broadcast read
    r1 += (ki < k1) ? 1 : 0;
    r2 += (ki < k2) ? 1 : 0;
  }

  int g = g0 + w;
  float4 Q = qS[w];
  if (lane < cnt && r1 >= 1 && r1 <= 16) {
    int om = (int)(k1 & 0xFFFFFFFFull);
    nb_idx[g*Kk + r1 - 1] = om;
    float4 Pm = pb4[om];
    p_out[(g*Kk + r1 - 1)*3 + 0] = __fsub_rn(Pm.x, Q.x);
    p_out[(g*Kk + r1 - 1)*3 + 1] = __fsub_rn(Pm.y, Q.y);
    p_out[(g*Kk + r1 - 1)*3 + 2] = __fsub_rn(Pm.z, Q.z);
  }
  if (lane + 64 < cnt && r2 >= 1 && r2 <= 16) {
    int om = (int)(k2 & 0xFFFFFFFFull);
    nb_idx[g*Kk + r2 - 1] = om;
    float4 Pm = pb4[om];
    p_out[(g*Kk + r2 - 1)*3 + 0] = __fsub_rn(Pm.x, Q.x);
    p_out[(g*Kk + r2 - 1)*3 + 1] = __fsub_rn(Pm.y, Q.y);
    p_out[(g*Kk + r2 - 1)*3 + 2] = __fsub_rn(Pm.z, Q.z);
  }
  if (lane < 3) rep_pos_out[g*3 + lane] = (lane == 0 ? Q.x : (lane == 1 ? Q.y : Q.z));
}

// ---------------- mlp v6: MG=4, depth-4 weight prefetch (covers L2 latency) ----------------
__device__ __forceinline__ void fma_g(float4& a, float hv, const float4& wv) {
  a.x = fmaf(hv, wv.x, a.x);
  a.y = fmaf(hv, wv.y, a.y);
  a.z = fmaf(hv, wv.z, a.z);
  a.w = fmaf(hv, wv.w, a.w);
}

__global__ __launch_bounds__(256) void mlp_kernel(
    const float* __restrict__ p,
    const float* __restrict__ t1t, const float* __restrict__ t1_b,
    const float* __restrict__ g1v, const float* __restrict__ b1v,
    const float* __restrict__ t2t, const float* __restrict__ t2_b,
    const float* __restrict__ g2v, const float* __restrict__ b2v,
    const float* __restrict__ t3t, const float* __restrict__ t3_b,
    const float* __restrict__ g3v, const float* __restrict__ b3v,
    float* __restrict__ T_out)
{
  __shared__ float pf[48][MG];       // 768 B
  __shared__ float hA[K2c][MG];      // 4 KB
  __shared__ float red[4*16*66];     // 16.9 KB: red[(w*16 + comp*4 + q)*66 + lane]
  int t = threadIdx.x;
  int w = t >> 6, l = t & 63;
  int g0 = blockIdx.x * MG;
  for (int e = t; e < MG*48; e += 256) {
    int g = e / 48, k = e - g*48;
    pf[k][g] = p[(size_t)(g0+g)*48 + k];
  }
  __syncthreads();

  float4 acc[MG];   // acc[q] = group q over cols 4l..4l+3

#define LDW(WSRC, K) (*(const float4*)&WSRC[(size_t)(K)*K2c + 4*l])

#define KSTAGE(WSRC, KDIM, HBUF, WB, KK, KNEXT)                        \
  {                                                                    \
    float4 wc = WB;                                                    \
    if ((KNEXT) < KDIM) WB = LDW(WSRC, KNEXT);                         \
    float4 h = *(const float4*)&HBUF[KK][0];                           \
    fma_g(acc[0], h.x, wc); fma_g(acc[1], h.y, wc);                    \
    fma_g(acc[2], h.z, wc); fma_g(acc[3], h.w, wc);                    \
  }

#define KLOOP(WSRC, KDIM, HBUF)                                        \
  {                                                                    \
    _Pragma("unroll")                                                  \
    for (int q = 0; q < MG; q++) acc[q] = make_float4(0.f,0.f,0.f,0.f);\
    float4 wb0 = LDW(WSRC, w);                                         \
    float4 wb1 = (w + 4  < KDIM) ? LDW(WSRC, w + 4)  : wb0;            \
    float4 wb2 = (w + 8  < KDIM) ? LDW(WSRC, w + 8)  : wb0;            \
    float4 wb3 = (w + 12 < KDIM) ? LDW(WSRC, w + 12) : wb0;            \
    for (int k = w; k < KDIM; k += 16) {                               \
      KSTAGE(WSRC, KDIM, HBUF, wb0, k,      k + 16)                    \
      if (k + 4 < KDIM)  KSTAGE(WSRC, KDIM, HBUF, wb1, k + 4,  k + 20) \
      if (k + 8 < KDIM)  KSTAGE(WSRC, KDIM, HBUF, wb2, k + 8,  k + 24) \
      if (k + 12 < KDIM) KSTAGE(WSRC, KDIM, HBUF, wb3, k + 12, k + 28) \
    }                                                                  \
  }

#define WRITE_RED()                                                    \
  {                                                                    \
    _Pragma("unroll")                                                  \
    for (int q = 0; q < MG; q++) {                                     \
      red[(w*16 + 0*4 + q)*66 + l] = acc[q].x;                         \
      red[(w*16 + 1*4 + q)*66 + l] = acc[q].y;                         \
      red[(w*16 + 2*4 + q)*66 + l] = acc[q].z;                         \
      red[(w*16 + 3*4 + q)*66 + l] = acc[q].w;                         \
    }                                                                  \
  }

#define REDUCE(S)                                                      \
  float4 S = make_float4(0.f,0.f,0.f,0.f);                             \
  {                                                                    \
    int lr = t >> 2, cc = t & 3;                                       \
    _Pragma("unroll")                                                  \
    for (int ww = 0; ww < 4; ww++) {                                   \
      S.x += red[(ww*16 + cc*4 + 0)*66 + lr];                          \
      S.y += red[(ww*16 + cc*4 + 1)*66 + lr];                          \
      S.z += red[(ww*16 + cc*4 + 2)*66 + lr];                          \
      S.w += red[(ww*16 + cc*4 + 3)*66 + lr];                          \
    }                                                                  \
  }

  // ===== layer 1 (K=48), relu =====
  KLOOP(t1t, 48, pf)
  WRITE_RED()
  __syncthreads();
  {
    REDUCE(s)
    float bb = t1_b[t], gg = g1v[t], oo = b1v[t];
    float4 v;
    v.x = fmaxf(fmaf(s.x + bb, gg, oo), 0.f);
    v.y = fmaxf(fmaf(s.y + bb, gg, oo), 0.f);
    v.z = fmaxf(fmaf(s.z + bb, gg, oo), 0.f);
    v.w = fmaxf(fmaf(s.w + bb, gg, oo), 0.f);
    *(float4*)&hA[t][0] = v;
  }
  __syncthreads();

  // ===== layer 2 (K=256), relu =====
  KLOOP(t2t, K2c, hA)
  WRITE_RED()
  __syncthreads();
  {
    REDUCE(s)
    float bb = t2_b[t], gg = g2v[t], oo = b2v[t];
    float4 v;
    v.x = fmaxf(fmaf(s.x + bb, gg, oo), 0.f);
    v.y = fmaxf(fmaf(s.y + bb, gg, oo), 0.f);
    v.z = fmaxf(fmaf(s.z + bb, gg, oo), 0.f);
    v.w = fmaxf(fmaf(s.w + bb, gg, oo), 0.f);
    *(float4*)&hA[t][0] = v;
  }
  __syncthreads();

  // ===== layer 3 (K=256), no relu, to global =====
  KLOOP(t3t, K2c, hA)
  WRITE_RED()
  __syncthreads();
  {
    REDUCE(s)
    float bb = t3_b[t], gg = g3v[t], oo = b3v[t];
    T_out[(size_t)(g0+0)*K2c + t] = fmaf(s.x + bb, gg, oo);
    T_out[(size_t)(g0+1)*K2c + t] = fmaf(s.y + bb, gg, oo);
    T_out[(size_t)(g0+2)*K2c + t] = fmaf(s.z + bb, gg, oo);
    T_out[(size_t)(g0+3)*K2c + t] = fmaf(s.w + bb, gg, oo);
  }
#undef KLOOP
#undef KSTAGE
#undef LDW
#undef WRITE_RED
#undef REDUCE
}

// ---------------- tf (fused feat), 4 groups/block ----------------
__global__ __launch_bounds__(256) void tf_kernel(
    const float* __restrict__ T_in, const float* __restrict__ features,
    const float* __restrict__ p, const int* __restrict__ nb_idx,
    const float* __restrict__ lift_w, const float* __restrict__ lift_b,
    const float* __restrict__ bng, const float* __restrict__ bnb,
    float* __restrict__ Tf)
{
  __shared__ float T_s[4*K2c];    // 4 KB
  __shared__ float f_s[4*KC];     // 20 KB
  __shared__ float ps[4*48];      // 768 B
  __shared__ int   idxs[64];      // 256 B
  __shared__ float lw[48], lb2[16], lg[16], lo[16];
  int t = threadIdx.x;
  int g0 = blockIdx.x * 4;
  int b = g0 / Rr;                // 4 | 2048: block never straddles batches
  for (int e = t; e < 4*K2c; e += 256) T_s[e] = T_in[(size_t)g0*K2c + e];
  if (t >= 32 && t < 224) {
    int e = t - 32;               // 192 threads cover ps
    ps[e] = p[(size_t)g0*48 + e];
  }
  if (t < 64) idxs[t] = nb_idx[g0*16 + t];
  if (t >= 64 && t < 112)  lw[t-64]   = lift_w[t-64];
  if (t >= 112 && t < 128) lb2[t-112] = lift_b[t-112];
  if (t >= 224 && t < 240) lg[t-224]  = bng[t-224];
  if (t >= 240)            lo[t-240]  = bnb[t-240];
  __syncthreads();

  // gather neighbor features: 64 rows of 64
  {
    int wv = t >> 6, ln = t & 63;
    for (int row = wv; row < 64; row += 4) {
      int gg = row >> 4, k = row & 15;
      f_s[gg*KC + k*FD + CL + ln] = features[((size_t)b*Nn + idxs[row])*CIN + ln];
    }
  }
  // lifted BN+ReLU: 4*16*16 = 1024 elements
  for (int e = t; e < 1024; e += 256) {
    int gg = e >> 8, rem = e & 255, k = rem >> 4, c = rem & 15;
    float acc = ps[gg*48 + k*3 + 0]*lw[c*3+0] + ps[gg*48 + k*3 + 1]*lw[c*3+1]
              + ps[gg*48 + k*3 + 2]*lw[c*3+2] + lb2[c];
    acc = acc*lg[c] + lo[c];
    f_s[gg*KC + k*FD + c] = fmaxf(acc, 0.f);
  }
  __syncthreads();

  int gg = t >> 6;    // wave per group
  int cl = t & 63;
  for (int ci = cl; ci < FD; ci += 64) {
    float fcol[16];
    #pragma unroll
    for (int j = 0; j < 16; j++) fcol[j] = f_s[gg*KC + j*FD + ci];
    #pragma unroll
    for (int k = 0; k < 16; k++) {
      float acc = 0.f;
      #pragma unroll
      for (int j = 0; j < 16; j++) acc = fmaf(T_s[gg*K2c + k*16 + j], fcol[j], acc);
      Tf[(size_t)(g0+gg)*KC + k*FD + ci] = acc;
    }
  }
}

// ---------------- gemm: out = Tf(4096x1280) @ Wp(1280x128), split-K=8 ----------------
__global__ __launch_bounds__(256) void gemm_kernel(
    const float* __restrict__ A,    // Tf
    const float* __restrict__ Bm,   // Wp
    float* __restrict__ part)       // [8][GT][COUT]
{
  __shared__ float As[16*36];
  __shared__ float Bs[16*COUT];
  int t = threadIdx.x;
  int m0 = blockIdx.x * 32;
  int ky = blockIdx.y;
  int kbase0 = ky * (KC/8);         // 160
  float acc[4][4];
  #pragma unroll
  for (int i = 0; i < 4; i++)
    #pragma unroll
    for (int j = 0; j < 4; j++) acc[i][j] = 0.f;
  int tn = t & 31, tm = t >> 5;

  for (int kt = 0; kt < KC/8; kt += 16) {
    int kb = kbase0 + kt;
    {
      int kcol = t & 15, row = t >> 4;
      As[kcol*36 + row]      = A[(size_t)(m0+row)*KC + kb + kcol];
      As[kcol*36 + row + 16] = A[(size_t)(m0+row+16)*KC + kb + kcol];
    }
    {
      int o = t & 127, kk2 = t >> 7;
      #pragma unroll
      for (int p4 = 0; p4 < 8; p4++) {
        int kk = kk2 + p4*2;
        Bs[kk*COUT + o] = Bm[(size_t)(kb+kk)*COUT + o];
      }
    }
    __syncthreads();
    #pragma unroll
    for (int kk = 0; kk < 16; kk++) {
      float4 a4 = *(const float4*)&As[kk*36 + tm*4];
      float4 b4 = *(const float4*)&Bs[kk*COUT + tn*4];
      float av[4] = {a4.x, a4.y, a4.z, a4.w};
      float bv[4] = {b4.x, b4.y, b4.z, b4.w};
      #pragma unroll
      for (int i = 0; i < 4; i++)
        #pragma unroll
        for (int j = 0; j < 4; j++) acc[i][j] = fmaf(av[i], bv[j], acc[i][j]);
    }
    __syncthreads();
  }
  #pragma unroll
  for (int i = 0; i < 4; i++) {
    float4 v = make_float4(acc[i][0], acc[i][1], acc[i][2], acc[i][3]);
    *(float4*)&part[((size_t)ky*GT + m0 + tm*4 + i)*COUT + tn*4] = v;
  }
}

// ---------------- reduce: out = sum(part[0..7]) + bias ----------------
__global__ __launch_bounds__(256) void reduce_kernel(
    const float* __restrict__ part, const float* __restrict__ conv_b,
    float* __restrict__ outp)
{
  int i = blockIdx.x*256 + threadIdx.x;
  float4 s = ((const float4*)conv_b)[i & 31];
  #pragma unroll
  for (int w = 0; w < 8; w++) {
    float4 v = ((const float4*)(part + (size_t)w*GT*COUT))[i];
    s.x += v.x; s.y += v.y; s.z += v.z; s.w += v.w;
  }
  ((float4*)outp)[i] = s;
}

extern "C" void kernel_launch(void* const* d_in, const int* in_sizes, int n_in,
                              void* d_out, int out_size, void* d_ws, size_t ws_size,
                              hipStream_t stream) {
  const float* points   = (const float*)d_in[0];
  const float* features = (const float*)d_in[1];
  const float* lift_w   = (const float*)d_in[2];
  const float* lift_b   = (const float*)d_in[3];
  const float* bn_lift_g= (const float*)d_in[4];
  const float* bn_lift_b= (const float*)d_in[5];
  const float* t1_w     = (const float*)d_in[6];
  const float* t1_b     = (const float*)d_in[7];
  const float* bn1_g    = (const float*)d_in[8];
  const float* bn1_b    = (const float*)d_in[9];
  const float* t2_w     = (const float*)d_in[10];
  const float* t2_b     = (const float*)d_in[11];
  const float* bn2_g    = (const float*)d_in[12];
  const float* bn2_b    = (const float*)d_in[13];
  const float* t3_w     = (const float*)d_in[14];
  const float* t3_b     = (const float*)d_in[15];
  const float* bn3_g    = (const float*)d_in[16];
  const float* bn3_b    = (const float*)d_in[17];
  const float* conv_w   = (const float*)d_in[18];
  const float* conv_b   = (const float*)d_in[19];
  const int*   rep_idx  = (const int*)d_in[20];

  char* ws = (char*)d_ws;
  int*    nb   = (int*)   (ws + 0);          // 256 KB
  float*  p    = (float*) (ws + 262144);     // 768 KB
  float*  T    = (float*) (ws + 1048576);    // 4 MB
  float*  Tf   = (float*) (ws + 5242880);    // 20 MB
  float*  wp   = (float*) (ws + 26214400);   // 640 KB
  float*  t1t  = (float*) (ws + 26869760);   // 48 KB
  float*  t2t  = (float*) (ws + 26918912);   // 256 KB
  float*  t3t  = (float*) (ws + 27181056);   // 256 KB
  float*  part = (float*) (ws + 33554432);   // 16 MB (8 splits)
  float4* pts4 = (float4*)(ws + 52428800);   // 256 KB

  float* rep_pos = (float*)d_out;
  float* outp    = (float*)d_out + (size_t)GT*3;

  prep_kernel<<<640, 256, 0, stream>>>(t1_w, t2_w, t3_w, conv_w, points,
                                       t1t, t2t, t3t, wp, pts4);
  knn_kernel<<<GT/8, 512, 0, stream>>>(pts4, rep_idx, nb, p, rep_pos);
  mlp_kernel<<<GT/MG, 256, 0, stream>>>(p, t1t, t1_b, bn1_g, bn1_b,
                                        t2t, t2_b, bn2_g, bn2_b,
                                        t3t, t3_b, bn3_g, bn3_b, T);
  tf_kernel<<<GT/4, 256, 0, stream>>>(T, features, p, nb,
                                      lift_w, lift_b, bn_lift_g, bn_lift_b, Tf);
  dim3 ggrid(GT/32, 8);
  gemm_kernel<<<ggrid, 256, 0, stream>>>(Tf, wp, part);
  reduce_kernel<<<(GT*COUT/4)/256, 256, 0, stream>>>(part, conv_b, outp);
}

// Round 4
// 209.930 us; speedup vs baseline: 1.0389x; 1.0234x over previous
//
#include <hip/hip_runtime.h>
#include <float.h>

#define Bn 2
#define Nn 8192
#define Rr 2048
#define Kk 16
#define CIN 64
#define CL 16
#define COUT 128
#define K2c 256
#define GT (Bn*Rr)      // 4096 groups
#define FD (CL+CIN)     // 80
#define KC (Kk*FD)      // 1280
#define MG 4            // mlp groups per block
#define CCAP 128        // knn candidate cap; expected count ~53 (v5.1 statistic)

// ---------------- prep: weight transposes / permute + pts4 packing ----------------
__global__ __launch_bounds__(256) void prep_kernel(
    const float* __restrict__ t1_w, const float* __restrict__ t2_w,
    const float* __restrict__ t3_w, const float* __restrict__ conv_w,
    const float* __restrict__ points,
    float* __restrict__ t1t, float* __restrict__ t2t,
    float* __restrict__ t3t, float* __restrict__ wp,
    float4* __restrict__ pts4)
{
  int i = blockIdx.x * 256 + threadIdx.x;
  if (i < K2c*48) { int j = i / 48, k = i - j*48; t1t[k*K2c + j] = t1_w[i]; }
  if (i < K2c*K2c) { int j = i >> 8, k = i & 255; t2t[k*K2c + j] = t2_w[i]; t3t[k*K2c + j] = t3_w[i]; }
  if (i < COUT*KC) {
    int o = i / KC, ck = i - o*KC;
    int c = ck >> 4, k = ck & 15;
    wp[(k*FD + c)*COUT + o] = conv_w[i];
  }
  if (i < Bn*Nn) {
    float x = points[i*3+0], y = points[i*3+1], z = points[i*3+2];
    // numpy order: sq = (x*x + y*y) + z*z, muls materialized then summed
    float sq = __fadd_rn(__fadd_rn(__fmul_rn(x,x), __fmul_rn(y,y)), __fmul_rn(z,z));
    pts4[i] = make_float4(x, y, z, sq);
  }
}

// ---------------- knn v9: v8 selection, streamed points (no reg residency) ----------------
// v8 post-mortem: holding P[16] (64 VGPRs) across both passes exceeded the
// launch_bounds VGPR cap -> compiler spilled the array to scratch ->
// WRITE_SIZE 33.8 MB / FETCH 17 MB of spill traffic, knn 60us, VALUBusy 22%.
// v9 keeps v8's harness-verified selection logic EXACTLY (bit-identical d2
// expressions, rank-select tau, atomic collect, rank extraction) but streams
// points from global in batches of 4 float4 per pass (16 live VGPRs). The
// 128 KB point cloud is L2-resident; pass-2 re-read ~3.8us of L2 BW. No
// LDS point staging, 4 barriers total, no serial shuffle chains.
__global__ __launch_bounds__(512, 4) void knn_kernel(
    const float4* __restrict__ pts4, const int* __restrict__ rep_idx,
    int* __restrict__ nb_idx, float* __restrict__ p_out,
    float* __restrict__ rep_pos_out)
{
  __shared__ float cbuf[8][512];                 // 16 KB per-thread minima [q][t]
  __shared__ unsigned long long coll[8][CCAP];   // 8 KB candidates
  __shared__ float Lst[8][64];                   // 2 KB per-lane tau stats
  __shared__ float4 qS[8];
  __shared__ float  tauS[8];
  __shared__ int    ccnt[8];

  int t    = threadIdx.x;
  int lane = t & 63;
  int w    = t >> 6;                 // 0..7
  int g0   = blockIdx.x * 8;         // 8 | 2048: block never straddles batches
  int b    = g0 >> 11;
  const float4* pb4 = pts4 + (size_t)b*Nn;

  if (t < 8) {
    int g = g0 + t;
    int r = g & 2047;
    qS[t] = pb4[rep_idx[r]];
    ccnt[t] = 0;
  }
  __syncthreads();

  // queries to SGPRs (uniform across block)
  float qx[8], qy[8], qz[8], qw[8];
  #pragma unroll
  for (int q = 0; q < 8; q++) {
    float4 Q = qS[q];
    qx[q] = __uint_as_float(__builtin_amdgcn_readfirstlane(__float_as_uint(Q.x)));
    qy[q] = __uint_as_float(__builtin_amdgcn_readfirstlane(__float_as_uint(Q.y)));
    qz[q] = __uint_as_float(__builtin_amdgcn_readfirstlane(__float_as_uint(Q.z)));
    qw[q] = __uint_as_float(__builtin_amdgcn_readfirstlane(__float_as_uint(Q.w)));
  }

  // ---- pass 1: per-thread min d2 per query; points streamed 4-at-a-time ----
  float m[8];
  #pragma unroll
  for (int q = 0; q < 8; q++) m[q] = FLT_MAX;
  for (int i0 = 0; i0 < 16; i0 += 4) {
    float4 P0 = pb4[t + 512*(i0+0)];
    float4 P1 = pb4[t + 512*(i0+1)];
    float4 P2 = pb4[t + 512*(i0+2)];
    float4 P3 = pb4[t + 512*(i0+3)];
    #pragma unroll
    for (int q = 0; q < 8; q++) {
      float d0 = __fsub_rn(__fadd_rn(qw[q], P0.w), __fmul_rn(2.0f,
                 __fmaf_rn(qz[q], P0.z, __fmaf_rn(qy[q], P0.y, __fmul_rn(qx[q], P0.x)))));
      float d1 = __fsub_rn(__fadd_rn(qw[q], P1.w), __fmul_rn(2.0f,
                 __fmaf_rn(qz[q], P1.z, __fmaf_rn(qy[q], P1.y, __fmul_rn(qx[q], P1.x)))));
      float d2 = __fsub_rn(__fadd_rn(qw[q], P2.w), __fmul_rn(2.0f,
                 __fmaf_rn(qz[q], P2.z, __fmaf_rn(qy[q], P2.y, __fmul_rn(qx[q], P2.x)))));
      float d3 = __fsub_rn(__fadd_rn(qw[q], P3.w), __fmul_rn(2.0f,
                 __fmaf_rn(qz[q], P3.z, __fmaf_rn(qy[q], P3.y, __fmul_rn(qx[q], P3.x)))));
      m[q] = fminf(fminf(fminf(m[q], d0), fminf(d1, d2)), d3);
    }
  }

  #pragma unroll
  for (int q = 0; q < 8; q++) cbuf[q][t] = m[q];
  __syncthreads();

  // ---- tau: wave w handles query w ----
  {
    // per-lane 3rd-smallest of its 8 thread-minima (bounds 3 real distances)
    float C0 = FLT_MAX, C1 = FLT_MAX, C2 = FLT_MAX;
    #pragma unroll
    for (int j = 0; j < 8; j++) {
      float v = cbuf[w][lane + 64*j];
      float n2 = __builtin_amdgcn_fmed3f(C1, C2, v);
      float n1 = __builtin_amdgcn_fmed3f(C0, C1, v);
      float n0 = fminf(C0, v);
      C0 = n0; C1 = n1; C2 = n2;
    }
    Lst[w][lane] = C2;
  }
  __syncthreads();
  {
    // tau = 6th-smallest L (rank 5, lex (L,lane) unique) -> >=18 pts <= tau
    float L = Lst[w][lane];
    int rk = 0;
    #pragma unroll 8
    for (int i = 0; i < 64; i++) {
      float Li = Lst[w][i];
      rk += (Li < L || (Li == L && i < lane)) ? 1 : 0;
    }
    if (rk == 5) tauS[w] = L;
  }
  __syncthreads();

  float tau[8];
  #pragma unroll
  for (int q = 0; q < 8; q++)
    tau[q] = __uint_as_float(__builtin_amdgcn_readfirstlane(__float_as_uint(tauS[q])));

  // ---- pass 2: re-stream points (L2-hot), predicate + collect ----
  for (int i0 = 0; i0 < 16; i0 += 4) {
    float4 Pb[4];
    Pb[0] = pb4[t + 512*(i0+0)];
    Pb[1] = pb4[t + 512*(i0+1)];
    Pb[2] = pb4[t + 512*(i0+2)];
    Pb[3] = pb4[t + 512*(i0+3)];
    #pragma unroll
    for (int u = 0; u < 4; u++) {
      float4 P = Pb[u];
      int idx = t + 512*(i0+u);
      #pragma unroll
      for (int q = 0; q < 8; q++) {
        float dot = __fmaf_rn(qz[q], P.z, __fmaf_rn(qy[q], P.y, __fmul_rn(qx[q], P.x)));
        float d2  = __fsub_rn(__fadd_rn(qw[q], P.w), __fmul_rn(2.0f, dot));
        if (d2 <= tau[q]) {
          int pos = atomicAdd(&ccnt[q], 1);
          if (pos < CCAP) {
            unsigned f = __float_as_uint(d2);
            unsigned mono = f ^ ((unsigned)((int)f >> 31) | 0x80000000u);
            coll[q][pos] = ((unsigned long long)mono << 32) | (unsigned)idx;
          }
        }
      }
    }
  }
  __syncthreads();

  // ---- extraction: exact rank via broadcast-compare (no serial chains) ----
  int cnt = __builtin_amdgcn_readfirstlane(ccnt[w]);
  if (cnt > CCAP) cnt = CCAP;
  unsigned long long k1 = (lane < cnt)      ? coll[w][lane]      : ~0ull;
  unsigned long long k2 = (lane + 64 < cnt) ? coll[w][lane + 64] : ~0ull;
  int r1 = 0, r2 = 0;
  for (int i = 0; i < cnt; i++) {
    unsigned long long ki = coll[w][i];   // broadcast read
    r1 += (ki < k1) ? 1 : 0;
    r2 += (ki < k2) ? 1 : 0;
  }

  int g = g0 + w;
  float4 Q = qS[w];
  if (lane < cnt && r1 >= 1 && r1 <= 16) {
    int om = (int)(k1 & 0xFFFFFFFFull);
    nb_idx[g*Kk + r1 - 1] = om;
    float4 Pm = pb4[om];
    p_out[(g*Kk + r1 - 1)*3 + 0] = __fsub_rn(Pm.x, Q.x);
    p_out[(g*Kk + r1 - 1)*3 + 1] = __fsub_rn(Pm.y, Q.y);
    p_out[(g*Kk + r1 - 1)*3 + 2] = __fsub_rn(Pm.z, Q.z);
  }
  if (lane + 64 < cnt && r2 >= 1 && r2 <= 16) {
    int om = (int)(k2 & 0xFFFFFFFFull);
    nb_idx[g*Kk + r2 - 1] = om;
    float4 Pm = pb4[om];
    p_out[(g*Kk + r2 - 1)*3 + 0] = __fsub_rn(Pm.x, Q.x);
    p_out[(g*Kk + r2 - 1)*3 + 1] = __fsub_rn(Pm.y, Q.y);
    p_out[(g*Kk + r2 - 1)*3 + 2] = __fsub_rn(Pm.z, Q.z);
  }
  if (lane < 3) rep_pos_out[g*3 + lane] = (lane == 0 ? Q.x : (lane == 1 ? Q.y : Q.z));
}

// ---------------- mlp v6: MG=4, depth-4 weight prefetch (covers L2 latency) ----------------
__device__ __forceinline__ void fma_g(float4& a, float hv, const float4& wv) {
  a.x = fmaf(hv, wv.x, a.x);
  a.y = fmaf(hv, wv.y, a.y);
  a.z = fmaf(hv, wv.z, a.z);
  a.w = fmaf(hv, wv.w, a.w);
}

__global__ __launch_bounds__(256) void mlp_kernel(
    const float* __restrict__ p,
    const float* __restrict__ t1t, const float* __restrict__ t1_b,
    const float* __restrict__ g1v, const float* __restrict__ b1v,
    const float* __restrict__ t2t, const float* __restrict__ t2_b,
    const float* __restrict__ g2v, const float* __restrict__ b2v,
    const float* __restrict__ t3t, const float* __restrict__ t3_b,
    const float* __restrict__ g3v, const float* __restrict__ b3v,
    float* __restrict__ T_out)
{
  __shared__ float pf[48][MG];       // 768 B
  __shared__ float hA[K2c][MG];      // 4 KB
  __shared__ float red[4*16*66];     // 16.9 KB: red[(w*16 + comp*4 + q)*66 + lane]
  int t = threadIdx.x;
  int w = t >> 6, l = t & 63;
  int g0 = blockIdx.x * MG;
  for (int e = t; e < MG*48; e += 256) {
    int g = e / 48, k = e - g*48;
    pf[k][g] = p[(size_t)(g0+g)*48 + k];
  }
  __syncthreads();

  float4 acc[MG];   // acc[q] = group q over cols 4l..4l+3

#define LDW(WSRC, K) (*(const float4*)&WSRC[(size_t)(K)*K2c + 4*l])

#define KSTAGE(WSRC, KDIM, HBUF, WB, KK, KNEXT)                        \
  {                                                                    \
    float4 wc = WB;                                                    \
    if ((KNEXT) < KDIM) WB = LDW(WSRC, KNEXT);                         \
    float4 h = *(const float4*)&HBUF[KK][0];                           \
    fma_g(acc[0], h.x, wc); fma_g(acc[1], h.y, wc);                    \
    fma_g(acc[2], h.z, wc); fma_g(acc[3], h.w, wc);                    \
  }

#define KLOOP(WSRC, KDIM, HBUF)                                        \
  {                                                                    \
    _Pragma("unroll")                                                  \
    for (int q = 0; q < MG; q++) acc[q] = make_float4(0.f,0.f,0.f,0.f);\
    float4 wb0 = LDW(WSRC, w);                                         \
    float4 wb1 = (w + 4  < KDIM) ? LDW(WSRC, w + 4)  : wb0;            \
    float4 wb2 = (w + 8  < KDIM) ? LDW(WSRC, w + 8)  : wb0;            \
    float4 wb3 = (w + 12 < KDIM) ? LDW(WSRC, w + 12) : wb0;            \
    for (int k = w; k < KDIM; k += 16) {                               \
      KSTAGE(WSRC, KDIM, HBUF, wb0, k,      k + 16)                    \
      if (k + 4 < KDIM)  KSTAGE(WSRC, KDIM, HBUF, wb1, k + 4,  k + 20) \
      if (k + 8 < KDIM)  KSTAGE(WSRC, KDIM, HBUF, wb2, k + 8,  k + 24) \
      if (k + 12 < KDIM) KSTAGE(WSRC, KDIM, HBUF, wb3, k + 12, k + 28) \
    }                                                                  \
  }

#define WRITE_RED()                                                    \
  {                                                                    \
    _Pragma("unroll")                                                  \
    for (int q = 0; q < MG; q++) {                                     \
      red[(w*16 + 0*4 + q)*66 + l] = acc[q].x;                         \
      red[(w*16 + 1*4 + q)*66 + l] = acc[q].y;                         \
      red[(w*16 + 2*4 + q)*66 + l] = acc[q].z;                         \
      red[(w*16 + 3*4 + q)*66 + l] = acc[q].w;                         \
    }                                                                  \
  }

#define REDUCE(S)                                                      \
  float4 S = make_float4(0.f,0.f,0.f,0.f);                             \
  {                                                                    \
    int lr = t >> 2, cc = t & 3;                                       \
    _Pragma("unroll")                                                  \
    for (int ww = 0; ww < 4; ww++) {                                   \
      S.x += red[(ww*16 + cc*4 + 0)*66 + lr];                          \
      S.y += red[(ww*16 + cc*4 + 1)*66 + lr];                          \
      S.z += red[(ww*16 + cc*4 + 2)*66 + lr];                          \
      S.w += red[(ww*16 + cc*4 + 3)*66 + lr];                          \
    }                                                                  \
  }

  // ===== layer 1 (K=48), relu =====
  KLOOP(t1t, 48, pf)
  WRITE_RED()
  __syncthreads();
  {
    REDUCE(s)
    float bb = t1_b[t], gg = g1v[t], oo = b1v[t];
    float4 v;
    v.x = fmaxf(fmaf(s.x + bb, gg, oo), 0.f);
    v.y = fmaxf(fmaf(s.y + bb, gg, oo), 0.f);
    v.z = fmaxf(fmaf(s.z + bb, gg, oo), 0.f);
    v.w = fmaxf(fmaf(s.w + bb, gg, oo), 0.f);
    *(float4*)&hA[t][0] = v;
  }
  __syncthreads();

  // ===== layer 2 (K=256), relu =====
  KLOOP(t2t, K2c, hA)
  WRITE_RED()
  __syncthreads();
  {
    REDUCE(s)
    float bb = t2_b[t], gg = g2v[t], oo = b2v[t];
    float4 v;
    v.x = fmaxf(fmaf(s.x + bb, gg, oo), 0.f);
    v.y = fmaxf(fmaf(s.y + bb, gg, oo), 0.f);
    v.z = fmaxf(fmaf(s.z + bb, gg, oo), 0.f);
    v.w = fmaxf(fmaf(s.w + bb, gg, oo), 0.f);
    *(float4*)&hA[t][0] = v;
  }
  __syncthreads();

  // ===== layer 3 (K=256), no relu, to global =====
  KLOOP(t3t, K2c, hA)
  WRITE_RED()
  __syncthreads();
  {
    REDUCE(s)
    float bb = t3_b[t], gg = g3v[t], oo = b3v[t];
    T_out[(size_t)(g0+0)*K2c + t] = fmaf(s.x + bb, gg, oo);
    T_out[(size_t)(g0+1)*K2c + t] = fmaf(s.y + bb, gg, oo);
    T_out[(size_t)(g0+2)*K2c + t] = fmaf(s.z + bb, gg, oo);
    T_out[(size_t)(g0+3)*K2c + t] = fmaf(s.w + bb, gg, oo);
  }
#undef KLOOP
#undef KSTAGE
#undef LDW
#undef WRITE_RED
#undef REDUCE
}

// ---------------- tf (fused feat), 4 groups/block ----------------
__global__ __launch_bounds__(256) void tf_kernel(
    const float* __restrict__ T_in, const float* __restrict__ features,
    const float* __restrict__ p, const int* __restrict__ nb_idx,
    const float* __restrict__ lift_w, const float* __restrict__ lift_b,
    const float* __restrict__ bng, const float* __restrict__ bnb,
    float* __restrict__ Tf)
{
  __shared__ float T_s[4*K2c];    // 4 KB
  __shared__ float f_s[4*KC];     // 20 KB
  __shared__ float ps[4*48];      // 768 B
  __shared__ int   idxs[64];      // 256 B
  __shared__ float lw[48], lb2[16], lg[16], lo[16];
  int t = threadIdx.x;
  int g0 = blockIdx.x * 4;
  int b = g0 / Rr;                // 4 | 2048: block never straddles batches
  for (int e = t; e < 4*K2c; e += 256) T_s[e] = T_in[(size_t)g0*K2c + e];
  if (t >= 32 && t < 224) {
    int e = t - 32;               // 192 threads cover ps
    ps[e] = p[(size_t)g0*48 + e];
  }
  if (t < 64) idxs[t] = nb_idx[g0*16 + t];
  if (t >= 64 && t < 112)  lw[t-64]   = lift_w[t-64];
  if (t >= 112 && t < 128) lb2[t-112] = lift_b[t-112];
  if (t >= 224 && t < 240) lg[t-224]  = bng[t-224];
  if (t >= 240)            lo[t-240]  = bnb[t-240];
  __syncthreads();

  // gather neighbor features: 64 rows of 64
  {
    int wv = t >> 6, ln = t & 63;
    for (int row = wv; row < 64; row += 4) {
      int gg = row >> 4, k = row & 15;
      f_s[gg*KC + k*FD + CL + ln] = features[((size_t)b*Nn + idxs[row])*CIN + ln];
    }
  }
  // lifted BN+ReLU: 4*16*16 = 1024 elements
  for (int e = t; e < 1024; e += 256) {
    int gg = e >> 8, rem = e & 255, k = rem >> 4, c = rem & 15;
    float acc = ps[gg*48 + k*3 + 0]*lw[c*3+0] + ps[gg*48 + k*3 + 1]*lw[c*3+1]
              + ps[gg*48 + k*3 + 2]*lw[c*3+2] + lb2[c];
    acc = acc*lg[c] + lo[c];
    f_s[gg*KC + k*FD + c] = fmaxf(acc, 0.f);
  }
  __syncthreads();

  int gg = t >> 6;    // wave per group
  int cl = t & 63;
  for (int ci = cl; ci < FD; ci += 64) {
    float fcol[16];
    #pragma unroll
    for (int j = 0; j < 16; j++) fcol[j] = f_s[gg*KC + j*FD + ci];
    #pragma unroll
    for (int k = 0; k < 16; k++) {
      float acc = 0.f;
      #pragma unroll
      for (int j = 0; j < 16; j++) acc = fmaf(T_s[gg*K2c + k*16 + j], fcol[j], acc);
      Tf[(size_t)(g0+gg)*KC + k*FD + ci] = acc;
    }
  }
}

// ---------------- gemm: out = Tf(4096x1280) @ Wp(1280x128), split-K=8 ----------------
__global__ __launch_bounds__(256) void gemm_kernel(
    const float* __restrict__ A,    // Tf
    const float* __restrict__ Bm,   // Wp
    float* __restrict__ part)       // [8][GT][COUT]
{
  __shared__ float As[16*36];
  __shared__ float Bs[16*COUT];
  int t = threadIdx.x;
  int m0 = blockIdx.x * 32;
  int ky = blockIdx.y;
  int kbase0 = ky * (KC/8);         // 160
  float acc[4][4];
  #pragma unroll
  for (int i = 0; i < 4; i++)
    #pragma unroll
    for (int j = 0; j < 4; j++) acc[i][j] = 0.f;
  int tn = t & 31, tm = t >> 5;

  for (int kt = 0; kt < KC/8; kt += 16) {
    int kb = kbase0 + kt;
    {
      int kcol = t & 15, row = t >> 4;
      As[kcol*36 + row]      = A[(size_t)(m0+row)*KC + kb + kcol];
      As[kcol*36 + row + 16] = A[(size_t)(m0+row+16)*KC + kb + kcol];
    }
    {
      int o = t & 127, kk2 = t >> 7;
      #pragma unroll
      for (int p4 = 0; p4 < 8; p4++) {
        int kk = kk2 + p4*2;
        Bs[kk*COUT + o] = Bm[(size_t)(kb+kk)*COUT + o];
      }
    }
    __syncthreads();
    #pragma unroll
    for (int kk = 0; kk < 16; kk++) {
      float4 a4 = *(const float4*)&As[kk*36 + tm*4];
      float4 b4 = *(const float4*)&Bs[kk*COUT + tn*4];
      float av[4] = {a4.x, a4.y, a4.z, a4.w};
      float bv[4] = {b4.x, b4.y, b4.z, b4.w};
      #pragma unroll
      for (int i = 0; i < 4; i++)
        #pragma unroll
        for (int j = 0; j < 4; j++) acc[i][j] = fmaf(av[i], bv[j], acc[i][j]);
    }
    __syncthreads();
  }
  #pragma unroll
  for (int i = 0; i < 4; i++) {
    float4 v = make_float4(acc[i][0], acc[i][1], acc[i][2], acc[i][3]);
    *(float4*)&part[((size_t)ky*GT + m0 + tm*4 + i)*COUT + tn*4] = v;
  }
}

// ---------------- reduce: out = sum(part[0..7]) + bias ----------------
__global__ __launch_bounds__(256) void reduce_kernel(
    const float* __restrict__ part, const float* __restrict__ conv_b,
    float* __restrict__ outp)
{
  int i = blockIdx.x*256 + threadIdx.x;
  float4 s = ((const float4*)conv_b)[i & 31];
  #pragma unroll
  for (int w = 0; w < 8; w++) {
    float4 v = ((const float4*)(part + (size_t)w*GT*COUT))[i];
    s.x += v.x; s.y += v.y; s.z += v.z; s.w += v.w;
  }
  ((float4*)outp)[i] = s;
}

extern "C" void kernel_launch(void* const* d_in, const int* in_sizes, int n_in,
                              void* d_out, int out_size, void* d_ws, size_t ws_size,
                              hipStream_t stream) {
  const float* points   = (const float*)d_in[0];
  const float* features = (const float*)d_in[1];
  const float* lift_w   = (const float*)d_in[2];
  const float* lift_b   = (const float*)d_in[3];
  const float* bn_lift_g= (const float*)d_in[4];
  const float* bn_lift_b= (const float*)d_in[5];
  const float* t1_w     = (const float*)d_in[6];
  const float* t1_b     = (const float*)d_in[7];
  const float* bn1_g    = (const float*)d_in[8];
  const float* bn1_b    = (const float*)d_in[9];
  const float* t2_w     = (const float*)d_in[10];
  const float* t2_b     = (const float*)d_in[11];
  const float* bn2_g    = (const float*)d_in[12];
  const float* bn2_b    = (const float*)d_in[13];
  const float* t3_w     = (const float*)d_in[14];
  const float* t3_b     = (const float*)d_in[15];
  const float* bn3_g    = (const float*)d_in[16];
  const float* bn3_b    = (const float*)d_in[17];
  const float* conv_w   = (const float*)d_in[18];
  const float* conv_b   = (const float*)d_in[19];
  const int*   rep_idx  = (const int*)d_in[20];

  char* ws = (char*)d_ws;
  int*    nb   = (int*)   (ws + 0);          // 256 KB
  float*  p    = (float*) (ws + 262144);     // 768 KB
  float*  T    = (float*) (ws + 1048576);    // 4 MB
  float*  Tf   = (float*) (ws + 5242880);    // 20 MB
  float*  wp   = (float*) (ws + 26214400);   // 640 KB
  float*  t1t  = (float*) (ws + 26869760);   // 48 KB
  float*  t2t  = (float*) (ws + 26918912);   // 256 KB
  float*  t3t  = (float*) (ws + 27181056);   // 256 KB
  float*  part = (float*) (ws + 33554432);   // 16 MB (8 splits)
  float4* pts4 = (float4*)(ws + 52428800);   // 256 KB

  float* rep_pos = (float*)d_out;
  float* outp    = (float*)d_out + (size_t)GT*3;

  prep_kernel<<<640, 256, 0, stream>>>(t1_w, t2_w, t3_w, conv_w, points,
                                       t1t, t2t, t3t, wp, pts4);
  knn_kernel<<<GT/8, 512, 0, stream>>>(pts4, rep_idx, nb, p, rep_pos);
  mlp_kernel<<<GT/MG, 256, 0, stream>>>(p, t1t, t1_b, bn1_g, bn1_b,
                                        t2t, t2_b, bn2_g, bn2_b,
                                        t3t, t3_b, bn3_g, bn3_b, T);
  tf_kernel<<<GT/4, 256, 0, stream>>>(T, features, p, nb,
                                      lift_w, lift_b, bn_lift_g, bn_lift_b, Tf);
  dim3 ggrid(GT/32, 8);
  gemm_kernel<<<ggrid, 256, 0, stream>>>(Tf, wp, part);
  reduce_kernel<<<(GT*COUT/4)/256, 256, 0, stream>>>(part, conv_b, outp);
}